// Round 6
// baseline (181.594 us; speedup 1.0000x reference)
//
#include <hip/hip_runtime.h>

#define BATCH 8
#define S_LEN 2048
#define DDIM 512
#define UDIM 512
#define WIN_L 128
#define WIN_R 128
#define PP 296   // P LDS pitch (f16): 288 + 8 (37 granules/row, conflict-free)

typedef _Float16 f16;
typedef __attribute__((ext_vector_type(8))) _Float16 f16x8;
typedef __attribute__((ext_vector_type(4))) _Float16 f16x4;
typedef __attribute__((ext_vector_type(4))) float f32x4;

__device__ __forceinline__ void gload_lds16(const void* g, void* l) {
  __builtin_amdgcn_global_load_lds((const __attribute__((address_space(1))) void*)g,
                                   (__attribute__((address_space(3))) void*)l, 16, 0, 0);
}

// ---------------- prep2: W [D][U] fp32 -> WT [U][D] f16  AND  X fp32 -> X16 f16 ----------------
__global__ void prep(const float* __restrict__ Wq, const float* __restrict__ Wk,
                     const float* __restrict__ Wv, const float* __restrict__ X32,
                     f16* __restrict__ WT, f16* __restrict__ X16) {
  int id = blockIdx.x;
  if (id < 768) {
    __shared__ float t[32][33];
    int zx = id & 15, zy = (id >> 4) & 15, zz = id >> 8;
    const float* W = zz == 0 ? Wq : (zz == 1 ? Wk : Wv);
    f16* WTz = WT + (size_t)zz * DDIM * UDIM;
    int tx = threadIdx.x & 31, ty = threadIdx.x >> 5;  // 32 x 8
    int n0 = zx * 32, k0 = zy * 32;
    for (int i = 0; i < 4; i++) {
      int r = ty * 4 + i;
      t[r][tx] = W[(size_t)(k0 + r) * UDIM + n0 + tx];
    }
    __syncthreads();
    for (int i = 0; i < 4; i++) {
      int r = ty * 4 + i;
      WTz[(size_t)(n0 + r) * DDIM + k0 + tx] = (f16)t[tx][r];
    }
  } else {
    size_t i0 = ((size_t)(id - 768) * 256 + threadIdx.x) * 8;
    float4 a = *(const float4*)(X32 + i0);
    float4 b = *(const float4*)(X32 + i0 + 4);
    f16x8 o;
    o[0] = (f16)a.x; o[1] = (f16)a.y; o[2] = (f16)a.z; o[3] = (f16)a.w;
    o[4] = (f16)b.x; o[5] = (f16)b.y; o[6] = (f16)b.z; o[7] = (f16)b.w;
    *(f16x8*)(X16 + i0) = o;
  }
}

// ---------------- QKV GEMM v7 (unchanged from round 4) ----------------
__global__ __launch_bounds__(256, 3) void gemm_qkv(
    const f16* __restrict__ X16, const f16* __restrict__ WT,
    const float* __restrict__ bq, const float* __restrict__ bk, const float* __restrict__ bv,
    f16* __restrict__ QKV, f16* __restrict__ VT) {
  int g = blockIdx.x;
  int xcd = g & 7, j = g >> 3;           // j in [0,192)
  int m_blk = xcd * 16 + (j & 15);       // 0..127
  int rest = j >> 4;                     // 0..11
  int ny = rest & 3, z = rest >> 2;      // ny 0..3, z 0..2

  const f16* WTz = WT + (size_t)z * DDIM * UDIM;   // [U][D] layout
  const float* bias = z == 0 ? bq : (z == 1 ? bk : bv);
  f16* out = QKV + (size_t)z * (BATCH * S_LEN) * UDIM;

  __shared__ f16 Al[2][128 * 32];        // [chunk] 16 KB
  __shared__ f16 Bl[2][128 * 32];        // [chunk] 16 KB

  int tid = threadIdx.x, wv = tid >> 6, ln = tid & 63;
  int m0 = m_blk * 128, n0 = ny * 128;
  int wm = (wv >> 1) * 64, wn = (wv & 1) * 64;
  int lm = ln & 15, lq = ln >> 4;
  int srow = ln >> 2;                                  // staging row within 16-row slab
  int scol = ((ln & 3) ^ ((ln >> 3) & 3)) * 8;         // swizzled 16B-chunk (source side)
  int rsw  = (lq ^ ((lm >> 1) & 3)) * 8;               // swizzled 16B-chunk (read side)

  f32x4 acc[4][4];
#pragma unroll
  for (int mt = 0; mt < 4; mt++)
    for (int nt = 0; nt < 4; nt++)
      for (int r = 0; r < 4; r++) acc[mt][nt][r] = 0.f;

  for (int k0 = 0; k0 < DDIM; k0 += 64) {
#pragma unroll
    for (int half = 0; half < 2; half++) {
      int r0 = half * 64 + wv * 16;  // wave-uniform
#pragma unroll
      for (int cc = 0; cc < 2; cc++) {
        gload_lds16(X16 + (size_t)(m0 + r0 + srow) * DDIM + k0 + cc * 32 + scol, &Al[cc][r0 * 32]);
        gload_lds16(WTz + (size_t)(n0 + r0 + srow) * DDIM + k0 + cc * 32 + scol, &Bl[cc][r0 * 32]);
      }
    }
    __syncthreads();

#pragma unroll
    for (int cc = 0; cc < 2; cc++) {
      f16x8 af[4], bfr[4];
#pragma unroll
      for (int mt = 0; mt < 4; mt++) af[mt] = *(const f16x8*)&Al[cc][(wm + mt * 16 + lm) * 32 + rsw];
#pragma unroll
      for (int nt = 0; nt < 4; nt++) bfr[nt] = *(const f16x8*)&Bl[cc][(wn + nt * 16 + lm) * 32 + rsw];
#pragma unroll
      for (int mt = 0; mt < 4; mt++)
#pragma unroll
        for (int nt = 0; nt < 4; nt++)
          acc[mt][nt] = __builtin_amdgcn_mfma_f32_16x16x32_f16(af[mt], bfr[nt], acc[mt][nt], 0, 0, 0);
    }
    __syncthreads();
  }

  if (z == 2) {
#pragma unroll
    for (int mt = 0; mt < 4; mt++)
#pragma unroll
      for (int nt = 0; nt < 4; nt++) {
        int col = n0 + wn + nt * 16 + lm;          // u
        float bv_ = bias[col];
        int row0 = m0 + wm + mt * 16 + lq * 4;     // global s index (r=0)
        int bb = row0 >> 11, ss = row0 & 2047;
        f16x4 o;
        for (int r = 0; r < 4; r++) o[r] = (f16)(acc[mt][nt][r] + bv_);
        *(f16x4*)&VT[((size_t)bb * UDIM + col) * S_LEN + ss] = o;
      }
  } else {
#pragma unroll
    for (int mt = 0; mt < 4; mt++)
#pragma unroll
      for (int nt = 0; nt < 4; nt++) {
        int col = n0 + wn + nt * 16 + lm;
        float bv_ = bias[col];
        for (int r = 0; r < 4; r++) {
          int row = m0 + wm + mt * 16 + lq * 4 + r;
          out[(size_t)row * UDIM + col] = (f16)(acc[mt][nt][r] + bv_);
        }
      }
  }
}

// ---------------- sliding-window attention v9: Q-in-LDS + static 2-buffer pipelines ----------------
// r5 diagnosis: VGPR=72 -> compiler rematerialized qf[16] (64 VGPR) from global per
// s-tile; each tile = ~32 dependent L2 loads vs 80 cyc MFMA -> MfmaUtil 5.6%.
// Fix: (a) Q staged once to LDS (swizzled, conflict-free ds_read_b128) so fragments
// can't be rematerialized from global; (b) K and V use explicit fully-unrolled
// ping-pong prefetch (named ka/kb, va/vb: static indexing, rule #20); (c) all 9
// tiles computed unconditionally (mask + address clamps already zero dead tiles) so
// the pipeline is branch-free. First V tiles issued before softmax barriers.
__global__ __launch_bounds__(256, 2) void attn(
    const f16* __restrict__ Q, const f16* __restrict__ K, const f16* __restrict__ VT,
    float* __restrict__ out) {
  __shared__ f16 Ql[32 * 512];                       // 32 KB, chunk ^= row&7
  __shared__ f16 Pb[32 * PP];                        // 18.9 KB
  __shared__ float wmax[2][32], wsum[2][32];

  int tid = threadIdx.x, wv = tid >> 6, ln = tid & 63;
  int lm = ln & 15, lq = ln >> 4;
  int b = blockIdx.x, q0 = blockIdx.y * 32;
  int rh = wv >> 1, kh = wv & 1;        // wave quarter: q-rows rh*16.., keys kh*16..
  const size_t base = (size_t)b * S_LEN;
  const int strip0 = q0 - WIN_L;        // strip keys [strip0, strip0+288)

  // ---- stage Q once: LDS[row][c] <- G[row][c ^ (row&7)] (verified swizzle pair) ----
#pragma unroll
  for (int i = 0; i < 8; i++) {
    int row = wv * 8 + i;
    gload_lds16(Q + (base + q0 + row) * (size_t)DDIM + (ln ^ i) * 8, &Ql[row * 512]);
  }
  __syncthreads();

  const int qrow = rh * 16 + lm;
  const int qsw = lm & 7;

  f32x4 sacc[9];
  f16x8 ka[16], kb[16];

#define LOAD_K(S, KF)                                                              \
  {                                                                                \
    int key_ = strip0 + (S) * 32 + kh * 16 + lm;                                   \
    int kc_ = key_ < 0 ? 0 : (key_ > S_LEN - 1 ? S_LEN - 1 : key_);                \
    const f16* kp_ = K + (base + kc_) * (size_t)DDIM + lq * 8;                     \
    _Pragma("unroll") for (int kk = 0; kk < 16; kk++)                              \
        KF[kk] = *(const f16x8*)(kp_ + kk * 32);                                   \
  }

#define S_TILE(S, KF)                                                              \
  {                                                                                \
    f32x4 s0_, s1_;                                                                \
    _Pragma("unroll") for (int r = 0; r < 4; r++) { s0_[r] = 0.f; s1_[r] = 0.f; }  \
    _Pragma("unroll") for (int kk = 0; kk < 16; kk += 2) {                         \
      f16x8 qa_ = *(const f16x8*)&Ql[qrow * 512 + ((kk * 4 + lq) ^ qsw) * 8];      \
      f16x8 qb_ = *(const f16x8*)&Ql[qrow * 512 + (((kk + 1) * 4 + lq) ^ qsw) * 8];\
      s0_ = __builtin_amdgcn_mfma_f32_16x16x32_f16(qa_, KF[kk], s0_, 0, 0, 0);     \
      s1_ = __builtin_amdgcn_mfma_f32_16x16x32_f16(qb_, KF[kk + 1], s1_, 0, 0, 0); \
    }                                                                              \
    _Pragma("unroll") for (int r = 0; r < 4; r++) sacc[S][r] = s0_[r] + s1_[r];    \
  }

  LOAD_K(0, ka);
  LOAD_K(1, kb);
  S_TILE(0, ka); LOAD_K(2, ka);
  S_TILE(1, kb); LOAD_K(3, kb);
  S_TILE(2, ka); LOAD_K(4, ka);
  S_TILE(3, kb); LOAD_K(5, kb);
  S_TILE(4, ka); LOAD_K(6, ka);
  S_TILE(5, kb); LOAD_K(7, kb);
  S_TILE(6, ka); LOAD_K(8, ka);
  S_TILE(7, kb);
  S_TILE(8, ka);

  // ---- V prefetch for tiles 0/1: latency hides under softmax + barriers ----
  f16x8 va[8], vb[8];
  const f16* vrow = VT + ((size_t)b * UDIM + wv * 128 + lm) * (size_t)S_LEN;
#define LOAD_V(S, VF)                                                              \
  {                                                                                \
    int key_ = strip0 + (S) * 32 + lq * 8;                                         \
    int kc_ = key_ < 0 ? 0 : (key_ > S_LEN - 8 ? S_LEN - 8 : key_);                \
    _Pragma("unroll") for (int nt = 0; nt < 8; nt++)                               \
        VF[nt] = *(const f16x8*)(vrow + (size_t)(nt * 16) * S_LEN + kc_);          \
  }
  LOAD_V(0, va);
  LOAD_V(1, vb);

  // ---- mask + row max (all 9 tiles; clamp+mask zeroes dead entries) ----
  const float scale = 0.044194173824159216f;  // 1/sqrt(512)
  float mx[4] = {-1e30f, -1e30f, -1e30f, -1e30f};
#pragma unroll
  for (int s = 0; s < 9; s++) {
    int kj = strip0 + s * 32 + kh * 16 + lm;
#pragma unroll
    for (int r = 0; r < 4; r++) {
      int qi = q0 + rh * 16 + lq * 4 + r;
      float v = sacc[s][r] * scale;
      bool ok = (kj >= 0) && (kj < S_LEN) && (kj >= qi - WIN_L) && (kj <= qi + WIN_R);
      v = ok ? v : -1e30f;
      sacc[s][r] = v;
      mx[r] = fmaxf(mx[r], v);
    }
  }
#pragma unroll
  for (int r = 0; r < 4; r++) {
    mx[r] = fmaxf(mx[r], __shfl_xor(mx[r], 1));
    mx[r] = fmaxf(mx[r], __shfl_xor(mx[r], 2));
    mx[r] = fmaxf(mx[r], __shfl_xor(mx[r], 4));
    mx[r] = fmaxf(mx[r], __shfl_xor(mx[r], 8));
  }
  if (lm == 0) {
#pragma unroll
    for (int r = 0; r < 4; r++) wmax[kh][rh * 16 + lq * 4 + r] = mx[r];
  }
  __syncthreads();

  // ---- exp + P park + row sums ----
  float mrow[4], sum[4] = {0.f, 0.f, 0.f, 0.f};
#pragma unroll
  for (int r = 0; r < 4; r++) {
    int row = rh * 16 + lq * 4 + r;
    mrow[r] = fmaxf(wmax[0][row], wmax[1][row]);
  }
#pragma unroll
  for (int s = 0; s < 9; s++) {
#pragma unroll
    for (int r = 0; r < 4; r++) {
      float p = __expf(sacc[s][r] - mrow[r]);
      sum[r] += p;
      Pb[(rh * 16 + lq * 4 + r) * PP + s * 32 + kh * 16 + lm] = (f16)p;
    }
  }
#pragma unroll
  for (int r = 0; r < 4; r++) {
    sum[r] += __shfl_xor(sum[r], 1);
    sum[r] += __shfl_xor(sum[r], 2);
    sum[r] += __shfl_xor(sum[r], 4);
    sum[r] += __shfl_xor(sum[r], 8);
  }
  if (lm == 0) {
#pragma unroll
    for (int r = 0; r < 4; r++) wsum[kh][rh * 16 + lq * 4 + r] = sum[r];
  }
  __syncthreads();  // Pb + sums visible

  // ---- PV phase: static ping-pong V prefetch ----
  f32x4 oacc[2][8];
#pragma unroll
  for (int mt = 0; mt < 2; mt++)
    for (int nt = 0; nt < 8; nt++)
      for (int r = 0; r < 4; r++) oacc[mt][nt][r] = 0.f;

#define PV_TILE(S, VF)                                                             \
  {                                                                                \
    f16x8 pf0_ = *(const f16x8*)&Pb[lm * PP + (S) * 32 + lq * 8];                  \
    f16x8 pf1_ = *(const f16x8*)&Pb[(16 + lm) * PP + (S) * 32 + lq * 8];           \
    _Pragma("unroll") for (int nt = 0; nt < 8; nt++) {                             \
      oacc[0][nt] = __builtin_amdgcn_mfma_f32_16x16x32_f16(pf0_, VF[nt], oacc[0][nt], 0, 0, 0); \
      oacc[1][nt] = __builtin_amdgcn_mfma_f32_16x16x32_f16(pf1_, VF[nt], oacc[1][nt], 0, 0, 0); \
    }                                                                              \
  }

  PV_TILE(0, va); LOAD_V(2, va);
  PV_TILE(1, vb); LOAD_V(3, vb);
  PV_TILE(2, va); LOAD_V(4, va);
  PV_TILE(3, vb); LOAD_V(5, vb);
  PV_TILE(4, va); LOAD_V(6, va);
  PV_TILE(5, vb); LOAD_V(7, vb);
  PV_TILE(6, va); LOAD_V(8, va);
  PV_TILE(7, vb);
  PV_TILE(8, va);

  // ---- epilogue: O /= l, fp32 store ----
  float linv[2][4];
#pragma unroll
  for (int mt = 0; mt < 2; mt++)
    for (int r = 0; r < 4; r++) {
      int row = mt * 16 + lq * 4 + r;
      linv[mt][r] = 1.0f / (wsum[0][row] + wsum[1][row]);
    }
#pragma unroll
  for (int mt = 0; mt < 2; mt++)
    for (int nt = 0; nt < 8; nt++)
      for (int r = 0; r < 4; r++) {
        int row = q0 + mt * 16 + lq * 4 + r;
        int col = wv * 128 + nt * 16 + lm;
        out[(base + row) * (size_t)UDIM + col] = oacc[mt][nt][r] * linv[mt][r];
      }
}

extern "C" void kernel_launch(void* const* d_in, const int* in_sizes, int n_in,
                              void* d_out, int out_size, void* d_ws, size_t ws_size,
                              hipStream_t stream) {
  const float* x  = (const float*)d_in[0];
  const float* Wq = (const float*)d_in[1];
  const float* Wk = (const float*)d_in[2];
  const float* Wv = (const float*)d_in[3];
  const float* bq = (const float*)d_in[4];
  const float* bk = (const float*)d_in[5];
  const float* bv = (const float*)d_in[6];
  float* out = (float*)d_out;

  char* ws = (char*)d_ws;
  const size_t WT_BYTES  = (size_t)3 * DDIM * UDIM * 2;            // 1.5 MB
  const size_t QKV_BYTES = (size_t)3 * BATCH * S_LEN * UDIM * 2;   // 50.3 MB
  const size_t VT_BYTES  = (size_t)BATCH * S_LEN * UDIM * 2;       // 16.8 MB
  f16* WT  = (f16*)ws;
  f16* QKV = (f16*)(ws + WT_BYTES);
  f16* VT  = (f16*)(ws + WT_BYTES + QKV_BYTES);
  f16* X16 = (f16*)(ws + WT_BYTES + QKV_BYTES + VT_BYTES);

  prep<<<768 + 4096, 256, 0, stream>>>(Wq, Wk, Wv, x, WT, X16);
  gemm_qkv<<<1536, 256, 0, stream>>>(X16, WT, bq, bk, bv, QKV, VT);
  // attn: blockIdx.x = batch so linear id % 8 == batch -> XCD-local K/V in L2
  attn<<<dim3(BATCH, S_LEN / 32), 256, 0, stream>>>(
      QKV, QKV + (size_t)BATCH * S_LEN * UDIM, VT, out);
}

// Round 7
// 151.704 us; speedup vs baseline: 1.1970x; 1.1970x over previous
//
#include <hip/hip_runtime.h>

#define BATCH 8
#define S_LEN 2048
#define DDIM 512
#define UDIM 512
#define WIN_L 128
#define WIN_R 128
#define PP 296    // gemm-era pitch (unused by attn v10)
#define PPX 328   // attn P pitch: 320 + 8 (41 granules/row -> conflict-free)

typedef _Float16 f16;
typedef __attribute__((ext_vector_type(8))) _Float16 f16x8;
typedef __attribute__((ext_vector_type(4))) _Float16 f16x4;
typedef __attribute__((ext_vector_type(4))) float f32x4;

__device__ __forceinline__ void gload_lds16(const void* g, void* l) {
  __builtin_amdgcn_global_load_lds((const __attribute__((address_space(1))) void*)g,
                                   (__attribute__((address_space(3))) void*)l, 16, 0, 0);
}

// ---------------- prep2: W [D][U] fp32 -> WT [U][D] f16  AND  X fp32 -> X16 f16 ----------------
__global__ void prep(const float* __restrict__ Wq, const float* __restrict__ Wk,
                     const float* __restrict__ Wv, const float* __restrict__ X32,
                     f16* __restrict__ WT, f16* __restrict__ X16) {
  int id = blockIdx.x;
  if (id < 768) {
    __shared__ float t[32][33];
    int zx = id & 15, zy = (id >> 4) & 15, zz = id >> 8;
    const float* W = zz == 0 ? Wq : (zz == 1 ? Wk : Wv);
    f16* WTz = WT + (size_t)zz * DDIM * UDIM;
    int tx = threadIdx.x & 31, ty = threadIdx.x >> 5;  // 32 x 8
    int n0 = zx * 32, k0 = zy * 32;
    for (int i = 0; i < 4; i++) {
      int r = ty * 4 + i;
      t[r][tx] = W[(size_t)(k0 + r) * UDIM + n0 + tx];
    }
    __syncthreads();
    for (int i = 0; i < 4; i++) {
      int r = ty * 4 + i;
      WTz[(size_t)(n0 + r) * DDIM + k0 + tx] = (f16)t[tx][r];
    }
  } else {
    size_t i0 = ((size_t)(id - 768) * 256 + threadIdx.x) * 8;
    float4 a = *(const float4*)(X32 + i0);
    float4 b = *(const float4*)(X32 + i0 + 4);
    f16x8 o;
    o[0] = (f16)a.x; o[1] = (f16)a.y; o[2] = (f16)a.z; o[3] = (f16)a.w;
    o[4] = (f16)b.x; o[5] = (f16)b.y; o[6] = (f16)b.z; o[7] = (f16)b.w;
    *(f16x8*)(X16 + i0) = o;
  }
}

// ---------------- QKV GEMM v7 (unchanged from round 4) ----------------
__global__ __launch_bounds__(256, 3) void gemm_qkv(
    const f16* __restrict__ X16, const f16* __restrict__ WT,
    const float* __restrict__ bq, const float* __restrict__ bk, const float* __restrict__ bv,
    f16* __restrict__ QKV, f16* __restrict__ VT) {
  int g = blockIdx.x;
  int xcd = g & 7, j = g >> 3;           // j in [0,192)
  int m_blk = xcd * 16 + (j & 15);       // 0..127
  int rest = j >> 4;                     // 0..11
  int ny = rest & 3, z = rest >> 2;      // ny 0..3, z 0..2

  const f16* WTz = WT + (size_t)z * DDIM * UDIM;   // [U][D] layout
  const float* bias = z == 0 ? bq : (z == 1 ? bk : bv);
  f16* out = QKV + (size_t)z * (BATCH * S_LEN) * UDIM;

  __shared__ f16 Al[2][128 * 32];        // [chunk] 16 KB
  __shared__ f16 Bl[2][128 * 32];        // [chunk] 16 KB

  int tid = threadIdx.x, wv = tid >> 6, ln = tid & 63;
  int m0 = m_blk * 128, n0 = ny * 128;
  int wm = (wv >> 1) * 64, wn = (wv & 1) * 64;
  int lm = ln & 15, lq = ln >> 4;
  int srow = ln >> 2;                                  // staging row within 16-row slab
  int scol = ((ln & 3) ^ ((ln >> 3) & 3)) * 8;         // swizzled 16B-chunk (source side)
  int rsw  = (lq ^ ((lm >> 1) & 3)) * 8;               // swizzled 16B-chunk (read side)

  f32x4 acc[4][4];
#pragma unroll
  for (int mt = 0; mt < 4; mt++)
    for (int nt = 0; nt < 4; nt++)
      for (int r = 0; r < 4; r++) acc[mt][nt][r] = 0.f;

  for (int k0 = 0; k0 < DDIM; k0 += 64) {
#pragma unroll
    for (int half = 0; half < 2; half++) {
      int r0 = half * 64 + wv * 16;  // wave-uniform
#pragma unroll
      for (int cc = 0; cc < 2; cc++) {
        gload_lds16(X16 + (size_t)(m0 + r0 + srow) * DDIM + k0 + cc * 32 + scol, &Al[cc][r0 * 32]);
        gload_lds16(WTz + (size_t)(n0 + r0 + srow) * DDIM + k0 + cc * 32 + scol, &Bl[cc][r0 * 32]);
      }
    }
    __syncthreads();

#pragma unroll
    for (int cc = 0; cc < 2; cc++) {
      f16x8 af[4], bfr[4];
#pragma unroll
      for (int mt = 0; mt < 4; mt++) af[mt] = *(const f16x8*)&Al[cc][(wm + mt * 16 + lm) * 32 + rsw];
#pragma unroll
      for (int nt = 0; nt < 4; nt++) bfr[nt] = *(const f16x8*)&Bl[cc][(wn + nt * 16 + lm) * 32 + rsw];
#pragma unroll
      for (int mt = 0; mt < 4; mt++)
#pragma unroll
        for (int nt = 0; nt < 4; nt++)
          acc[mt][nt] = __builtin_amdgcn_mfma_f32_16x16x32_f16(af[mt], bfr[nt], acc[mt][nt], 0, 0, 0);
    }
    __syncthreads();
  }

  if (z == 2) {
#pragma unroll
    for (int mt = 0; mt < 4; mt++)
#pragma unroll
      for (int nt = 0; nt < 4; nt++) {
        int col = n0 + wn + nt * 16 + lm;          // u
        float bv_ = bias[col];
        int row0 = m0 + wm + mt * 16 + lq * 4;     // global s index (r=0)
        int bb = row0 >> 11, ss = row0 & 2047;
        f16x4 o;
        for (int r = 0; r < 4; r++) o[r] = (f16)(acc[mt][nt][r] + bv_);
        *(f16x4*)&VT[((size_t)bb * UDIM + col) * S_LEN + ss] = o;
      }
  } else {
#pragma unroll
    for (int mt = 0; mt < 4; mt++)
#pragma unroll
      for (int nt = 0; nt < 4; nt++) {
        int col = n0 + wn + nt * 16 + lm;
        float bv_ = bias[col];
        for (int r = 0; r < 4; r++) {
          int row = m0 + wm + mt * 16 + lq * 4 + r;
          out[(size_t)row * UDIM + col] = (f16)(acc[mt][nt][r] + bv_);
        }
      }
  }
}

// ---------------- attention v10: 512-thr / 64 q-rows, 3-buffer LDS ring + counted vmcnt ----------------
// r6 lesson: reg-prefetch of K/V tiles is register-infeasible -> compiler sinks loads
// (load->use serial, 5.8% MfmaUtil). Only gload_lds + counted vmcnt can't be sunk.
// Ring: tile t reads buf[t%3], stages t+2 into buf[(t+2)%3] (never the read buffer)
// -> ONE raw barrier per tile, vmcnt(4) only (never 0 in-loop). Q pinned in regs via
// volatile asm (kills r5-style remat, keeps vmcnt counts pure).
#define BARR  __builtin_amdgcn_s_barrier()
#define SCHB  __builtin_amdgcn_sched_barrier(0)
#define WAITV4 asm volatile("s_waitcnt vmcnt(4)" ::: "memory")
#define WAITV0 asm volatile("s_waitcnt vmcnt(0)" ::: "memory")

__global__ __launch_bounds__(512, 2) void attn(
    const f16* __restrict__ Q, const f16* __restrict__ K, const f16* __restrict__ VT,
    float* __restrict__ out) {
  __shared__ f16 ring[3 * 16384];                    // 3 x 32 KB K/V tile ring
  __shared__ f16 Pb[64 * PPX];                       // 41 KB
  __shared__ float wmax[2][64], wsum[2][64];
  f16* B0 = ring;
  f16* B1 = ring + 16384;
  f16* B2 = ring + 32768;

  int tid = threadIdx.x, wv = tid >> 6, ln = tid & 63;
  int lm = ln & 15, lq = ln >> 4;
  int qg = wv >> 1, kh = wv & 1;        // S-phase: q-group (16 rows), key-half
  int rh2 = wv >> 2, cw = wv & 3;       // PV-phase: row-half (32 rows), col-span (128 u)
  int b = blockIdx.x, q0 = blockIdx.y * 64;
  const size_t base = (size_t)b * S_LEN;
  const int strip0 = q0 - WIN_L;        // keys [strip0, strip0+320)

  // ---- Q fragments: load once, drain, PIN (no remat possible afterwards) ----
  f16x8 qf[16];
  {
    const f16* qrow = Q + (base + q0 + qg * 16 + lm) * (size_t)DDIM + lq * 8;
#pragma unroll
    for (int kk = 0; kk < 16; kk++) qf[kk] = *(const f16x8*)(qrow + kk * 32);
  }
  WAITV0;
  SCHB;
#pragma unroll
  for (int kk = 0; kk < 16; kk++) asm volatile("" : "+v"(qf[kk]));

#define STAGE_K(S, DST)                                                            \
  {                                                                                \
    _Pragma("unroll") for (int i_ = 0; i_ < 4; i_++) {                             \
      int row_ = wv * 4 + i_;                                                      \
      int key_ = strip0 + (S) * 32 + row_;                                         \
      int kc_ = key_ < 0 ? 0 : (key_ > S_LEN - 1 ? S_LEN - 1 : key_);              \
      gload_lds16(K + (base + kc_) * (size_t)DDIM + (ln ^ (row_ & 7)) * 8,         \
                  (DST) + row_ * 512);                                             \
    }                                                                              \
  }

  f32x4 sacc[10];
#define S_TILE(S, SRC)                                                             \
  {                                                                                \
    const f16* kl_ = (SRC);                                                        \
    int krow_ = kh * 16 + lm;                                                      \
    f32x4 s0_, s1_;                                                                \
    _Pragma("unroll") for (int r = 0; r < 4; r++) { s0_[r] = 0.f; s1_[r] = 0.f; }  \
    _Pragma("unroll") for (int kk = 0; kk < 16; kk += 2) {                         \
      f16x8 k0_ = *(const f16x8*)&kl_[krow_ * 512 + ((kk * 4 + lq) ^ (lm & 7)) * 8];          \
      f16x8 k1_ = *(const f16x8*)&kl_[krow_ * 512 + (((kk + 1) * 4 + lq) ^ (lm & 7)) * 8];    \
      s0_ = __builtin_amdgcn_mfma_f32_16x16x32_f16(qf[kk], k0_, s0_, 0, 0, 0);     \
      s1_ = __builtin_amdgcn_mfma_f32_16x16x32_f16(qf[kk + 1], k1_, s1_, 0, 0, 0); \
    }                                                                              \
    _Pragma("unroll") for (int r = 0; r < 4; r++) sacc[S][r] = s0_[r] + s1_[r];    \
  }

  // ---- S pipeline: tile t in buf[t%3]; stage t+2 after compute ----
  STAGE_K(0, B0); STAGE_K(1, B1);
  WAITV4; BARR; SCHB; S_TILE(0, B0); STAGE_K(2, B2);
  WAITV4; BARR; SCHB; S_TILE(1, B1); STAGE_K(3, B0);
  WAITV4; BARR; SCHB; S_TILE(2, B2); STAGE_K(4, B1);
  WAITV4; BARR; SCHB; S_TILE(3, B0); STAGE_K(5, B2);
  WAITV4; BARR; SCHB; S_TILE(4, B1); STAGE_K(6, B0);
  WAITV4; BARR; SCHB; S_TILE(5, B2); STAGE_K(7, B1);
  WAITV4; BARR; SCHB; S_TILE(6, B0); STAGE_K(8, B2);
  WAITV4; BARR; SCHB; S_TILE(7, B1); STAGE_K(9, B0);
  WAITV4; BARR; SCHB; S_TILE(8, B2);
  WAITV0; BARR; SCHB; S_TILE(9, B0);

  // ---- mask + row max ----
  const float scale = 0.044194173824159216f;  // 1/sqrt(512)
  float mx[4] = {-1e30f, -1e30f, -1e30f, -1e30f};
#pragma unroll
  for (int s = 0; s < 10; s++) {
    int kj = strip0 + s * 32 + kh * 16 + lm;
#pragma unroll
    for (int r = 0; r < 4; r++) {
      int qi = q0 + qg * 16 + lq * 4 + r;
      float v = sacc[s][r] * scale;
      bool ok = (kj >= 0) && (kj < S_LEN) && (kj >= qi - WIN_L) && (kj <= qi + WIN_R);
      v = ok ? v : -1e30f;
      sacc[s][r] = v;
      mx[r] = fmaxf(mx[r], v);
    }
  }
#pragma unroll
  for (int r = 0; r < 4; r++) {
    mx[r] = fmaxf(mx[r], __shfl_xor(mx[r], 1));
    mx[r] = fmaxf(mx[r], __shfl_xor(mx[r], 2));
    mx[r] = fmaxf(mx[r], __shfl_xor(mx[r], 4));
    mx[r] = fmaxf(mx[r], __shfl_xor(mx[r], 8));
  }
  if (lm == 0) {
#pragma unroll
    for (int r = 0; r < 4; r++) wmax[kh][qg * 16 + lq * 4 + r] = mx[r];
  }
  __syncthreads();  // barrier A: wmax visible; all K reads done (vmem queue empty -> free drain)

#define STAGE_V(S, DST)                                                            \
  {                                                                                \
    int kc0_ = strip0 + (S) * 32;                                                  \
    kc0_ = kc0_ < 0 ? 0 : (kc0_ > S_LEN - 32 ? S_LEN - 32 : kc0_);                 \
    int sc_ = ((ln & 3) ^ ((ln >> 4) & 3)) * 8;                                    \
    _Pragma("unroll") for (int i_ = 0; i_ < 4; i_++) {                             \
      int u0_ = wv * 64 + i_ * 16;                                                 \
      gload_lds16(VT + ((size_t)b * UDIM + u0_ + (ln >> 2)) * (size_t)S_LEN + kc0_ + sc_, \
                  (DST) + u0_ * 32);                                               \
    }                                                                              \
  }

  STAGE_V(0, B0); STAGE_V(1, B1);  // latency hides under exp/park below

  // ---- exp + P park + row sums ----
  float mrow[4], sum[4] = {0.f, 0.f, 0.f, 0.f};
#pragma unroll
  for (int r = 0; r < 4; r++) {
    int row = qg * 16 + lq * 4 + r;
    mrow[r] = fmaxf(wmax[0][row], wmax[1][row]);
  }
#pragma unroll
  for (int s = 0; s < 10; s++) {
#pragma unroll
    for (int r = 0; r < 4; r++) {
      float p = __expf(sacc[s][r] - mrow[r]);
      sum[r] += p;
      Pb[(qg * 16 + lq * 4 + r) * PPX + s * 32 + kh * 16 + lm] = (f16)p;
    }
  }
#pragma unroll
  for (int r = 0; r < 4; r++) {
    sum[r] += __shfl_xor(sum[r], 1);
    sum[r] += __shfl_xor(sum[r], 2);
    sum[r] += __shfl_xor(sum[r], 4);
    sum[r] += __shfl_xor(sum[r], 8);
  }
  if (lm == 0) {
#pragma unroll
    for (int r = 0; r < 4; r++) wsum[kh][qg * 16 + lq * 4 + r] = sum[r];
  }
  __syncthreads();  // barrier B: Pb + wsum visible (drains V0/V1 early; they're needed next anyway)

  // ---- PV pipeline: same ring ----
  f32x4 oacc[2][8];
#pragma unroll
  for (int mt = 0; mt < 2; mt++)
    for (int nt = 0; nt < 8; nt++)
      for (int r = 0; r < 4; r++) oacc[mt][nt][r] = 0.f;

#define PV_TILE(S, SRC)                                                            \
  {                                                                                \
    const f16* vl_ = (SRC);                                                        \
    f16x8 pf0_ = *(const f16x8*)&Pb[(rh2 * 32 + lm) * PPX + (S) * 32 + lq * 8];    \
    f16x8 pf1_ = *(const f16x8*)&Pb[(rh2 * 32 + 16 + lm) * PPX + (S) * 32 + lq * 8]; \
    _Pragma("unroll") for (int nt = 0; nt < 8; nt++) {                             \
      f16x8 vf_ = *(const f16x8*)&vl_[(cw * 128 + nt * 16 + lm) * 32 + (lq ^ ((lm >> 2) & 3)) * 8]; \
      oacc[0][nt] = __builtin_amdgcn_mfma_f32_16x16x32_f16(pf0_, vf_, oacc[0][nt], 0, 0, 0); \
      oacc[1][nt] = __builtin_amdgcn_mfma_f32_16x16x32_f16(pf1_, vf_, oacc[1][nt], 0, 0, 0); \
    }                                                                              \
  }

  WAITV4; BARR; SCHB; PV_TILE(0, B0); STAGE_V(2, B2);
  WAITV4; BARR; SCHB; PV_TILE(1, B1); STAGE_V(3, B0);
  WAITV4; BARR; SCHB; PV_TILE(2, B2); STAGE_V(4, B1);
  WAITV4; BARR; SCHB; PV_TILE(3, B0); STAGE_V(5, B2);
  WAITV4; BARR; SCHB; PV_TILE(4, B1); STAGE_V(6, B0);
  WAITV4; BARR; SCHB; PV_TILE(5, B2); STAGE_V(7, B1);
  WAITV4; BARR; SCHB; PV_TILE(6, B0); STAGE_V(8, B2);
  WAITV4; BARR; SCHB; PV_TILE(7, B1); STAGE_V(9, B0);
  WAITV4; BARR; SCHB; PV_TILE(8, B2);
  WAITV0; BARR; SCHB; PV_TILE(9, B0);

  // ---- epilogue: O /= l, fp32 store ----
  float linv[2][4];
#pragma unroll
  for (int mt = 0; mt < 2; mt++)
    for (int r = 0; r < 4; r++) {
      int row = rh2 * 32 + mt * 16 + lq * 4 + r;
      linv[mt][r] = 1.0f / (wsum[0][row] + wsum[1][row]);
    }
#pragma unroll
  for (int mt = 0; mt < 2; mt++)
    for (int nt = 0; nt < 8; nt++)
      for (int r = 0; r < 4; r++) {
        int row = q0 + rh2 * 32 + mt * 16 + lq * 4 + r;
        int col = cw * 128 + nt * 16 + lm;
        out[(base + row) * (size_t)UDIM + col] = oacc[mt][nt][r] * linv[mt][r];
      }
}

extern "C" void kernel_launch(void* const* d_in, const int* in_sizes, int n_in,
                              void* d_out, int out_size, void* d_ws, size_t ws_size,
                              hipStream_t stream) {
  const float* x  = (const float*)d_in[0];
  const float* Wq = (const float*)d_in[1];
  const float* Wk = (const float*)d_in[2];
  const float* Wv = (const float*)d_in[3];
  const float* bq = (const float*)d_in[4];
  const float* bk = (const float*)d_in[5];
  const float* bv = (const float*)d_in[6];
  float* out = (float*)d_out;

  char* ws = (char*)d_ws;
  const size_t WT_BYTES  = (size_t)3 * DDIM * UDIM * 2;            // 1.5 MB
  const size_t QKV_BYTES = (size_t)3 * BATCH * S_LEN * UDIM * 2;   // 50.3 MB
  const size_t VT_BYTES  = (size_t)BATCH * S_LEN * UDIM * 2;       // 16.8 MB
  f16* WT  = (f16*)ws;
  f16* QKV = (f16*)(ws + WT_BYTES);
  f16* VT  = (f16*)(ws + WT_BYTES + QKV_BYTES);
  f16* X16 = (f16*)(ws + WT_BYTES + QKV_BYTES + VT_BYTES);

  prep<<<768 + 4096, 256, 0, stream>>>(Wq, Wk, Wv, x, WT, X16);
  gemm_qkv<<<1536, 256, 0, stream>>>(X16, WT, bq, bk, bv, QKV, VT);
  // attn: 512 thr / 64 q-rows; blockIdx.x = batch -> XCD-local K/V in L2
  attn<<<dim3(BATCH, S_LEN / 64), 512, 0, stream>>>(
      QKV, QKV + (size_t)BATCH * S_LEN * UDIM, VT, out);
}